// Round 1
// baseline (192.354 us; speedup 1.0000x reference)
//
#include <hip/hip_runtime.h>

// EdgeCompute: per-edge  out = sigmoid( relu(|x[src]-x[dst]| @ W1 + b1) @ W2 + b2 )
// N_NODES=10000, N_EDGES=640000, D_FEAT=128, HID=64
//
// Strategy (fp32, VALU-roofline ~67us):
//  - 1 lane = 1 edge; 64 fp32 accumulators per lane = all HID outputs.
//  - W1/b1/W2/b2 indexed only by uniform values -> compiler promotes to s_load,
//    inner loop is v_fma_f32 acc, v_d, s_w (1 instr per MAC, no LDS traffic).
//  - x-row gathers: float4 per lane, double-buffered across 16-element k-chunks
//    to hide L2 gather latency (~200-900cyc) at ~2 waves/SIMD occupancy.
//  - outer k-chunk loop kept rolled (#pragma unroll 1): 1024-FMA body (~8KB)
//    avoids I-cache thrash from a fully unrolled 8192-FMA body.

#define D_FEAT 128
#define HID 64

__global__ __launch_bounds__(256, 2) void edge_mlp_f32(
    const float* __restrict__ x,
    const int* __restrict__ idx,
    const float* __restrict__ W1,
    const float* __restrict__ b1,
    const float* __restrict__ W2,
    const float* __restrict__ b2,
    float* __restrict__ out,
    int n_edges)
{
    const int edge = blockIdx.x * blockDim.x + threadIdx.x;
    if (edge >= n_edges) return;

    const int s = idx[edge];
    const int d = idx[n_edges + edge];

    const float4* __restrict__ ps = (const float4*)(x + (size_t)s * D_FEAT);
    const float4* __restrict__ pd = (const float4*)(x + (size_t)d * D_FEAT);

    // acc[j] = b1[j] (b1 uniform -> s_load)
    float acc[HID];
#pragma unroll
    for (int j = 0; j < HID; ++j) acc[j] = b1[j];

    // preload chunk 0 (k = 0..15 -> float4 indices 0..3 of each row)
    float4 ca[4], cb[4];
#pragma unroll
    for (int q = 0; q < 4; ++q) { ca[q] = ps[q]; cb[q] = pd[q]; }

#pragma unroll 1
    for (int c = 0; c < 8; ++c) {
        // prefetch next chunk (wraps to 0 on last iter; harmless L1 hit)
        const int nc = (c + 1) & 7;
        float4 na[4], nb[4];
#pragma unroll
        for (int q = 0; q < 4; ++q) { na[q] = ps[nc * 4 + q]; nb[q] = pd[nc * 4 + q]; }

        // d = |xs - xd| for this 16-wide k chunk
        float dv[16];
#pragma unroll
        for (int q = 0; q < 4; ++q) {
            dv[q * 4 + 0] = fabsf(ca[q].x - cb[q].x);
            dv[q * 4 + 1] = fabsf(ca[q].y - cb[q].y);
            dv[q * 4 + 2] = fabsf(ca[q].z - cb[q].z);
            dv[q * 4 + 3] = fabsf(ca[q].w - cb[q].w);
        }

        // acc[j] += dv[k] * W1[k_global][j]; W1 index uniform -> s_load operand
#pragma unroll
        for (int k = 0; k < 16; ++k) {
            const float dk = dv[k];
            const float* __restrict__ wrow = W1 + (c * 16 + k) * HID;
#pragma unroll
            for (int j = 0; j < HID; ++j)
                acc[j] = fmaf(dk, wrow[j], acc[j]);
        }

#pragma unroll
        for (int q = 0; q < 4; ++q) { ca[q] = na[q]; cb[q] = nb[q]; }
    }

    // layer 2: t = sum_j relu(h_j) * W2[j] + b2 ; out = sigmoid(t)
    float t = b2[0];
#pragma unroll
    for (int j = 0; j < HID; ++j)
        t = fmaf(fmaxf(acc[j], 0.0f), W2[j], t);

    out[edge] = __builtin_amdgcn_rcpf(1.0f + __expf(-t));
}

extern "C" void kernel_launch(void* const* d_in, const int* in_sizes, int n_in,
                              void* d_out, int out_size, void* d_ws, size_t ws_size,
                              hipStream_t stream) {
    const float* x   = (const float*)d_in[0];
    const int*   idx = (const int*)d_in[1];
    const float* W1  = (const float*)d_in[2];
    const float* b1  = (const float*)d_in[3];
    const float* W2  = (const float*)d_in[4];
    const float* b2  = (const float*)d_in[5];
    float* out = (float*)d_out;

    const int n_edges = in_sizes[1] / 2;   // indices is [2, n_edges]
    const int block = 256;
    const int grid = (n_edges + block - 1) / block;

    edge_mlp_f32<<<grid, block, 0, stream>>>(x, idx, W1, b1, W2, b2, out, n_edges);
}

// Round 2
// 156.928 us; speedup vs baseline: 1.2258x; 1.2258x over previous
//
#include <hip/hip_runtime.h>

// EdgeCompute via MFMA: out = sigmoid( relu(|x[s]-x[d]| @ W1 + b1) @ W2 + b2 )
// N_EDGES=640000, D_FEAT=128, HID=64.
//
// Per wave: 64 edges. [64x128] @ [128x64] = 4 m-tiles x 4 n-tiles x 4 k-blocks
// of mfma_f32_16x16x32_bf16. fp32 accuracy via bf16 hi/lo split:
//   acc += Ahi*Bhi + Ahi*Blo + Alo*Bhi   (error ~2^-14/term, negligible)
// W1 hi/lo fragments staged in LDS (32KB/block, filled once).
// A fragments gathered directly from global in MFMA layout:
//   A[m=lane&15][k=(lane>>4)*8+j]  -> lane loads 8 contiguous floats of its
//   edge's rows (32B chunks; 4 lanes cover 128B of a row -> coalesced-ish).
// C/D layout (m89/m91 verified): col(n)=lane&15, row(m)=(lane>>4)*4+reg.

#define DF 128
#define HID 64

typedef __attribute__((ext_vector_type(8))) short short8;
typedef __attribute__((ext_vector_type(4))) float floatx4;

__device__ __forceinline__ void split_bf16(float v, short& hi, short& lo) {
    unsigned u = __float_as_uint(v);
    unsigned hb = u & 0xFFFF0000u;            // truncate-to-bf16 (hi)
    float lof = v - __uint_as_float(hb);      // exact in fp32
    hi = (short)(u >> 16);
    lo = (short)(__float_as_uint(lof) >> 16); // truncate lo: err <= 2^-14 |v|
}

__global__ __launch_bounds__(256, 2) void edge_mlp_mfma(
    const float* __restrict__ x,
    const int* __restrict__ idx,
    const float* __restrict__ W1,
    const float* __restrict__ b1,
    const float* __restrict__ W2,
    const float* __restrict__ b2,
    float* __restrict__ out,
    int n_edges)
{
    // B fragments: [kb][nt][lane][8] bf16, hi and lo. 16KB each.
    __shared__ short lds_bhi[4 * 4 * 64 * 8];
    __shared__ short lds_blo[4 * 4 * 64 * 8];

    const int tid = threadIdx.x;

    // ---- stage W1 hi/lo fragments into LDS (once per block) ----
#pragma unroll 1
    for (int slot = tid; slot < 1024; slot += 256) {
        const int lane = slot & 63;
        const int nt = (slot >> 6) & 3;
        const int kb = slot >> 8;
        const int kbase = kb * 32 + (lane >> 4) * 8;
        const int n = nt * 16 + (lane & 15);
        short8 vh, vl;
#pragma unroll
        for (int j = 0; j < 8; ++j) {
            short h, l;
            split_bf16(W1[(size_t)(kbase + j) * HID + n], h, l);
            vh[j] = h; vl[j] = l;
        }
        *reinterpret_cast<short8*>(&lds_bhi[slot * 8]) = vh;
        *reinterpret_cast<short8*>(&lds_blo[slot * 8]) = vl;
    }
    __syncthreads();

    const int w = tid >> 6;          // wave in block
    const int L = tid & 63;          // lane
    const int r16 = L & 15;          // m (A) / n (B) / col (C)
    const int q = L >> 4;            // quad
    const long base = (long)blockIdx.x * 256 + (long)w * 64;

    // endpoint indices for this lane's 4 edges (one per m-tile)
    int se[4], de[4];
#pragma unroll
    for (int mt = 0; mt < 4; ++mt) {
        long e = base + mt * 16 + r16;
        if (e >= n_edges) e = n_edges - 1;
        se[mt] = idx[e];
        de[mt] = idx[(long)n_edges + e];
    }

    floatx4 acc[4][4];
#pragma unroll
    for (int mt = 0; mt < 4; ++mt)
#pragma unroll
        for (int nt = 0; nt < 4; ++nt)
            acc[mt][nt] = (floatx4){0.f, 0.f, 0.f, 0.f};

#pragma unroll 1
    for (int kb = 0; kb < 4; ++kb) {
        const int koff = kb * 32 + q * 8;

        // A fragments: |x[s] - x[d]| for 8 k's, hi/lo bf16
        short8 ahi[4], alo[4];
#pragma unroll
        for (int mt = 0; mt < 4; ++mt) {
            const float* ps = x + (size_t)se[mt] * DF + koff;
            const float* pd = x + (size_t)de[mt] * DF + koff;
            float4 s0 = *(const float4*)ps;
            float4 s1 = *(const float4*)(ps + 4);
            float4 d0 = *(const float4*)pd;
            float4 d1 = *(const float4*)(pd + 4);
            float dv[8];
            dv[0] = fabsf(s0.x - d0.x); dv[1] = fabsf(s0.y - d0.y);
            dv[2] = fabsf(s0.z - d0.z); dv[3] = fabsf(s0.w - d0.w);
            dv[4] = fabsf(s1.x - d1.x); dv[5] = fabsf(s1.y - d1.y);
            dv[6] = fabsf(s1.z - d1.z); dv[7] = fabsf(s1.w - d1.w);
#pragma unroll
            for (int j = 0; j < 8; ++j) {
                short h, l;
                split_bf16(dv[j], h, l);
                ahi[mt][j] = h; alo[mt][j] = l;
            }
        }

#pragma unroll
        for (int nt = 0; nt < 4; ++nt) {
            const int slot = kb * 256 + nt * 64 + L;
            short8 bh = *reinterpret_cast<short8*>(&lds_bhi[slot * 8]);
            short8 bl = *reinterpret_cast<short8*>(&lds_blo[slot * 8]);
#pragma unroll
            for (int mt = 0; mt < 4; ++mt) {
                acc[mt][nt] = __builtin_amdgcn_mfma_f32_16x16x32_bf16(ahi[mt], bh, acc[mt][nt], 0, 0, 0);
                acc[mt][nt] = __builtin_amdgcn_mfma_f32_16x16x32_bf16(ahi[mt], bl, acc[mt][nt], 0, 0, 0);
                acc[mt][nt] = __builtin_amdgcn_mfma_f32_16x16x32_bf16(alo[mt], bh, acc[mt][nt], 0, 0, 0);
            }
        }
    }

    // ---- layer 2 + sigmoid ----
    float b1v[4], w2v[4];
#pragma unroll
    for (int nt = 0; nt < 4; ++nt) {
        const int n = nt * 16 + r16;
        b1v[nt] = b1[n];
        w2v[nt] = W2[n];
    }
    const float b2v = b2[0];

#pragma unroll
    for (int mt = 0; mt < 4; ++mt) {
        float part[4] = {0.f, 0.f, 0.f, 0.f};
#pragma unroll
        for (int nt = 0; nt < 4; ++nt) {
#pragma unroll
            for (int r = 0; r < 4; ++r) {
                float h = acc[mt][nt][r] + b1v[nt];
                h = fmaxf(h, 0.f);
                part[r] = fmaf(h, w2v[nt], part[r]);
            }
        }
        // reduce over the 16 lanes sharing the same rows (bits 0..3 of lane)
#pragma unroll
        for (int r = 0; r < 4; ++r) {
            float p = part[r];
            p += __shfl_xor(p, 1, 64);
            p += __shfl_xor(p, 2, 64);
            p += __shfl_xor(p, 4, 64);
            p += __shfl_xor(p, 8, 64);
            part[r] = p;
        }
        if (r16 < 4) {
            // lane (16q + r) stores row q*4 + r of this m-tile
            const float t = part[r16] + b2v;
            const long e = base + mt * 16 + q * 4 + r16;
            if (e < n_edges)
                out[e] = __builtin_amdgcn_rcpf(1.0f + __expf(-t));
        }
    }
}

extern "C" void kernel_launch(void* const* d_in, const int* in_sizes, int n_in,
                              void* d_out, int out_size, void* d_ws, size_t ws_size,
                              hipStream_t stream) {
    const float* x   = (const float*)d_in[0];
    const int*   idx = (const int*)d_in[1];
    const float* W1  = (const float*)d_in[2];
    const float* b1  = (const float*)d_in[3];
    const float* W2  = (const float*)d_in[4];
    const float* b2  = (const float*)d_in[5];
    float* out = (float*)d_out;

    const int n_edges = in_sizes[1] / 2;           // indices is [2, n_edges]
    const int edges_per_block = 256;               // 4 waves x 64 edges
    const int grid = (n_edges + edges_per_block - 1) / edges_per_block;

    edge_mlp_mfma<<<grid, 256, 0, stream>>>(x, idx, W1, b1, W2, b2, out, n_edges);
}

// Round 3
// 126.945 us; speedup vs baseline: 1.5153x; 1.2362x over previous
//
#include <hip/hip_runtime.h>

// EdgeCompute v3: coalesced row gather + f16 MFMA.
//   out = sigmoid( relu(|x[s]-x[d]| @ W1 + b1) @ W2 + b2 )
// N_EDGES=640000, D_FEAT=128, HID=64.
//
// Round-2 lesson: per-lane random-row gather = 64 distinct cachelines per
// load instruction -> TA/TCP request-rate bound (~67us of line processing).
// Fix: wave loads 2 FULL rows per instruction (32 lanes x 16B = 512B row),
// 100% line utilization, 16x fewer line-requests. s/d rows paired in regs,
// |diff| in fp32, cvt f16 (err ~2^-11, ~1e-4 at output), staged to padded
// per-wave LDS in A-fragment order; single f16 MFMA (no hi/lo).
// Wave tile = 16 edges -> low VGPR -> 4 waves/SIMD; LDS 33.8KB -> 4 blk/CU.

#define DF 128
#define HID 64
#define ASTRIDE 136   // f16 per A row: 128 + 8 pad (272B = 17*16B, keeps b128 align)

typedef _Float16 half8 __attribute__((ext_vector_type(8)));
typedef _Float16 half4_t __attribute__((ext_vector_type(4)));
typedef float floatx4 __attribute__((ext_vector_type(4)));

__global__ __launch_bounds__(256, 4) void edge_mlp_v3(
    const float* __restrict__ x,
    const int* __restrict__ idx,
    const float* __restrict__ W1,
    const float* __restrict__ b1,
    const float* __restrict__ W2,
    const float* __restrict__ b2,
    float* __restrict__ out,
    int n_edges, int ngroups)
{
    // B fragments (W1 as f16): [kb][nt][lane][8] = 16KB
    __shared__ __attribute__((aligned(16))) _Float16 lds_b[4 * 4 * 64 * 8];
    // A fragments per wave: [m=16][k=128 (+pad)] f16 = 4.25KB x 4 waves
    __shared__ __attribute__((aligned(16))) _Float16 lds_a[4][16 * ASTRIDE];

    const int tid = threadIdx.x;

    // ---- stage W1 -> f16 B fragments (once per block) ----
#pragma unroll
    for (int i = 0; i < 4; ++i) {
        const int slot = i * 256 + tid;
        const int lane = slot & 63;
        const int nt = (slot >> 6) & 3;
        const int kb = slot >> 8;
        const int kbase = kb * 32 + (lane >> 4) * 8;
        const int n = nt * 16 + (lane & 15);
        half8 v;
#pragma unroll
        for (int j = 0; j < 8; ++j)
            v[j] = (_Float16)W1[(size_t)(kbase + j) * HID + n];
        *(half8*)(lds_b + slot * 8) = v;
    }
    __syncthreads();

    const int w = tid >> 6;       // wave in block
    const int L = tid & 63;       // lane
    const int r16 = L & 15;
    const int q = L >> 4;
    const int c = L & 31;         // 16B chunk index within a 512B row
    const int hi = L >> 5;        // which row of the pair this half-wave loads
    _Float16* const pa = &lds_a[w][0];

    // loop-invariant epilogue params (n = nt*16 + r16)
    float b1v[4], w2v[4];
#pragma unroll
    for (int nt = 0; nt < 4; ++nt) {
        b1v[nt] = b1[nt * 16 + r16];
        w2v[nt] = W2[nt * 16 + r16];
    }
    const float b2v = b2[0];

    for (int g = blockIdx.x; g < ngroups; g += gridDim.x) {
        const int eb = g * 64 + w * 16;   // this wave's 16 edges

        // per-lane rowid table: lane r (r=L&31) holds row r of [s0..s15,d0..d15]
        int er = eb + r16;
        if (er >= n_edges) er = n_edges - 1;
        const int rid = idx[(size_t)((L & 16) ? n_edges : 0) + er];

        // ---- coalesced gather: 2 full rows per instruction ----
        float4 sv[8], dv[8];
#pragma unroll
        for (int p = 0; p < 8; ++p) {
            const int id = __shfl(rid, p * 2 + hi, 64);        // s-row p*2+hi
            sv[p] = *(const float4*)(x + (size_t)id * DF + c * 4);
        }
#pragma unroll
        for (int p = 0; p < 8; ++p) {
            const int id = __shfl(rid, 16 + p * 2 + hi, 64);   // d-row
            dv[p] = *(const float4*)(x + (size_t)id * DF + c * 4);
        }

        // ---- diff -> f16 -> per-wave A-fragment LDS ----
#pragma unroll
        for (int p = 0; p < 8; ++p) {
            const int m = p * 2 + hi;   // edge within wave tile
            half4_t h;
            h[0] = (_Float16)fabsf(sv[p].x - dv[p].x);
            h[1] = (_Float16)fabsf(sv[p].y - dv[p].y);
            h[2] = (_Float16)fabsf(sv[p].z - dv[p].z);
            h[3] = (_Float16)fabsf(sv[p].w - dv[p].w);
            *(half4_t*)(pa + m * ASTRIDE + c * 4) = h;
        }
        // same-wave DS ops are in order; compiler inserts lgkmcnt before reads.

        // ---- MFMA: [16x128] @ [128x64] ----
        floatx4 acc[4];
#pragma unroll
        for (int nt = 0; nt < 4; ++nt) acc[nt] = (floatx4){0.f, 0.f, 0.f, 0.f};

#pragma unroll
        for (int kb = 0; kb < 4; ++kb) {
            const half8 af = *(const half8*)(pa + r16 * ASTRIDE + kb * 32 + q * 8);
#pragma unroll
            for (int nt = 0; nt < 4; ++nt) {
                const half8 bf = *(const half8*)(lds_b + (kb * 256 + nt * 64 + L) * 8);
                acc[nt] = __builtin_amdgcn_mfma_f32_16x16x32_f16(af, bf, acc[nt], 0, 0, 0);
            }
        }

        // ---- layer 2 + sigmoid ----
        // C layout: col(n within tile)=L&15, row(m)=q*4+reg
        float part[4] = {0.f, 0.f, 0.f, 0.f};
#pragma unroll
        for (int nt = 0; nt < 4; ++nt) {
#pragma unroll
            for (int r = 0; r < 4; ++r) {
                const float hh = fmaxf(acc[nt][r] + b1v[nt], 0.f);
                part[r] = fmaf(hh, w2v[nt], part[r]);
            }
        }
#pragma unroll
        for (int r = 0; r < 4; ++r) {
            float pp = part[r];
            pp += __shfl_xor(pp, 1, 64);
            pp += __shfl_xor(pp, 2, 64);
            pp += __shfl_xor(pp, 4, 64);
            pp += __shfl_xor(pp, 8, 64);
            part[r] = pp;
        }
        if (r16 < 4) {
            const int e = eb + q * 4 + r16;
            if (e < n_edges) {
                const float t = part[r16] + b2v;
                out[e] = __builtin_amdgcn_rcpf(1.0f + __expf(-t));
            }
        }
    }
}

extern "C" void kernel_launch(void* const* d_in, const int* in_sizes, int n_in,
                              void* d_out, int out_size, void* d_ws, size_t ws_size,
                              hipStream_t stream) {
    const float* x   = (const float*)d_in[0];
    const int*   idx = (const int*)d_in[1];
    const float* W1  = (const float*)d_in[2];
    const float* b1  = (const float*)d_in[3];
    const float* W2  = (const float*)d_in[4];
    const float* b2  = (const float*)d_in[5];
    float* out = (float*)d_out;

    const int n_edges = in_sizes[1] / 2;          // indices is [2, n_edges]
    const int ngroups = (n_edges + 63) / 64;      // 64 edges per block-iteration
    int grid = ngroups < 2560 ? ngroups : 2560;   // grid-stride; amortize W1 staging

    edge_mlp_v3<<<grid, 256, 0, stream>>>(x, idx, W1, b1, W2, b2, out,
                                          n_edges, ngroups);
}

// Round 4
// 110.528 us; speedup vs baseline: 1.7403x; 1.1485x over previous
//
#include <hip/hip_runtime.h>

// EdgeCompute v4: L2-resident f16 x + transposed MFMA + scalar idx + pipeline.
//   out = sigmoid( relu(|x[s]-x[d]| @ W1 + b1) @ W2 + b2 )
// N_EDGES=640000, D_FEAT=128, HID=64.
//
// Round-3 lessons: (a) fp32 x (5.1MB) thrashes 4MB/XCD L2 -> 113MB HBM fetch;
// (b) DS pipe ~480cyc/iter (B-frag re-reads + 32 bpermutes) ~ 31us/CU;
// (c) serial per-iter chain, 2.7 waves/SIMD.
// Fixes: x->f16 in d_ws (2.56MB, L2-resident; 4 rows/wave-load);
// transposed MFMA D[hid][edge]: A=W1^T in 64 VGPRs (no per-iter B LDS reads),
// epilogue reduce = 2 shfl_xor; scalar s_load idx (no rid bpermutes);
// ids 2-deep + rows 1-deep software pipeline; zero barriers (per-wave LDS).

#define DF 128
#define HID 64
#define AST 136   // halfs per diff row (272B = 17*16B; +4-bank row skew, 2-way free)

typedef _Float16 half8  __attribute__((ext_vector_type(8)));
typedef _Float16 half4_t __attribute__((ext_vector_type(4)));
typedef float    floatx4 __attribute__((ext_vector_type(4)));

__device__ __forceinline__ float sigmoidf_(float t) {
    return __builtin_amdgcn_rcpf(1.0f + __expf(-t));
}

// ---- pre-pass: x f32 -> f16 into workspace ----
__global__ void cvt_x_f16(const float* __restrict__ x, _Float16* __restrict__ xh, int n4) {
    int i = blockIdx.x * blockDim.x + threadIdx.x;
    if (i < n4) {
        float4 v = ((const float4*)x)[i];
        half4_t h = { (_Float16)v.x, (_Float16)v.y, (_Float16)v.z, (_Float16)v.w };
        ((half4_t*)xh)[i] = h;
    }
}

template<bool F16X>
__global__ __launch_bounds__(256, 3) void edge_mlp_v4(
    const float* __restrict__ x, const _Float16* __restrict__ xh,
    const int* __restrict__ idx,
    const float* __restrict__ W1, const float* __restrict__ b1,
    const float* __restrict__ W2, const float* __restrict__ b2,
    float* __restrict__ out, int n_edges, int ngroups, int gstride)
{
    __shared__ __attribute__((aligned(16))) _Float16 lds_d[4][16 * AST];

    const int tid = threadIdx.x;
    const int w   = __builtin_amdgcn_readfirstlane(tid) >> 6;  // uniform wave id
    const int L   = tid & 63;
    const int r16 = L & 15, q = L >> 4;
    _Float16* const ldsw = &lds_d[w][0];

    // ---- W1^T A-fragments -> registers (once per block) ----
    // A[m=hid=mt*16+r16][k=feat=kb*32+q*8+j]
    half8 wf[4][4];
#pragma unroll
    for (int mt = 0; mt < 4; ++mt)
#pragma unroll
        for (int kb = 0; kb < 4; ++kb)
#pragma unroll
            for (int j = 0; j < 8; ++j)
                wf[mt][kb][j] = (_Float16)W1[(size_t)(kb * 32 + q * 8 + j) * HID + mt * 16 + r16];

    // per-lane epilogue constants (hid = mt*16 + q*4 + r), packed f16
    half4_t b1h[4], w2h[4];
#pragma unroll
    for (int mt = 0; mt < 4; ++mt)
#pragma unroll
        for (int r = 0; r < 4; ++r) {
            b1h[mt][r] = (_Float16)b1[mt * 16 + q * 4 + r];
            w2h[mt][r] = (_Float16)W2[mt * 16 + q * 4 + r];
        }
    const float b2v = b2[0];

    // lane roles for the gather
    const int rp = L >> 4;   // f16 path: which of 4 rows per load
    const int c2 = L & 15;   // f16 path: 16B chunk in 256B row
    const int hi = L >> 5;   // f32 path: which of 2 rows per load
    const int c  = L & 31;   // f32 path: 16B chunk in 512B row

    // ---------------- pipeline preamble ----------------
    const int g0 = blockIdx.x;
    int sc[16], dc[16];                      // ids for the group whose ROWS we load next
    {
        const int eb = g0 * 64 + w * 16;
        const int* __restrict__ ip = idx + eb;
        const int* __restrict__ jp = idx + n_edges + eb;
#pragma unroll
        for (int i = 0; i < 16; ++i) { sc[i] = ip[i]; dc[i] = jp[i]; }
    }

    // gather + diff for g0 -> LDS
    auto gather_diff = [&](const int* s_, const int* d_) {
        if (F16X) {
            half8 rs[4], rd[4];
#pragma unroll
            for (int p = 0; p < 4; ++p) {
                int ia = (rp & 2) ? s_[4 * p + 2] : s_[4 * p + 0];
                int ib = (rp & 2) ? s_[4 * p + 3] : s_[4 * p + 1];
                int id = (rp & 1) ? ib : ia;
                rs[p] = *(const half8*)(xh + (size_t)id * DF + c2 * 8);
            }
#pragma unroll
            for (int p = 0; p < 4; ++p) {
                int ia = (rp & 2) ? d_[4 * p + 2] : d_[4 * p + 0];
                int ib = (rp & 2) ? d_[4 * p + 3] : d_[4 * p + 1];
                int id = (rp & 1) ? ib : ia;
                rd[p] = *(const half8*)(xh + (size_t)id * DF + c2 * 8);
            }
#pragma unroll
            for (int p = 0; p < 4; ++p) {
                union { half8 h; uint4 u; } U;
                U.h = rs[p] - rd[p];
                U.u.x &= 0x7FFF7FFFu; U.u.y &= 0x7FFF7FFFu;
                U.u.z &= 0x7FFF7FFFu; U.u.w &= 0x7FFF7FFFu;
                *(half8*)(ldsw + (4 * p + rp) * AST + c2 * 8) = U.h;
            }
        } else {
            float4 rs[8], rd[8];
#pragma unroll
            for (int p = 0; p < 8; ++p) {
                int id = hi ? s_[2 * p + 1] : s_[2 * p];
                rs[p] = *(const float4*)(x + (size_t)id * DF + c * 4);
            }
#pragma unroll
            for (int p = 0; p < 8; ++p) {
                int id = hi ? d_[2 * p + 1] : d_[2 * p];
                rd[p] = *(const float4*)(x + (size_t)id * DF + c * 4);
            }
#pragma unroll
            for (int p = 0; p < 8; ++p) {
                half4_t h;
                h[0] = (_Float16)fabsf(rs[p].x - rd[p].x);
                h[1] = (_Float16)fabsf(rs[p].y - rd[p].y);
                h[2] = (_Float16)fabsf(rs[p].z - rd[p].z);
                h[3] = (_Float16)fabsf(rs[p].w - rd[p].w);
                *(half4_t*)(ldsw + (2 * p + hi) * AST + c * 4) = h;
            }
        }
    };
    gather_diff(sc, dc);   // LDS now holds g0

    // preload ids for g0+gstride
    {
        int g1 = g0 + gstride; if (g1 >= ngroups) g1 = g0;
        const int eb = g1 * 64 + w * 16;
        const int* __restrict__ ip = idx + eb;
        const int* __restrict__ jp = idx + n_edges + eb;
#pragma unroll
        for (int i = 0; i < 16; ++i) { sc[i] = ip[i]; dc[i] = jp[i]; }
    }

    // ---------------- main loop (no barriers) ----------------
#pragma unroll 1
    for (int g = g0; g < ngroups; g += gstride) {
        // 1) issue next group's row loads (ids held in sc/dc)
        half8 rs16[4], rd16[4];
        float4 rs32[8], rd32[8];
        if (F16X) {
#pragma unroll
            for (int p = 0; p < 4; ++p) {
                int ia = (rp & 2) ? sc[4 * p + 2] : sc[4 * p + 0];
                int ib = (rp & 2) ? sc[4 * p + 3] : sc[4 * p + 1];
                int id = (rp & 1) ? ib : ia;
                rs16[p] = *(const half8*)(xh + (size_t)id * DF + c2 * 8);
            }
#pragma unroll
            for (int p = 0; p < 4; ++p) {
                int ia = (rp & 2) ? dc[4 * p + 2] : dc[4 * p + 0];
                int ib = (rp & 2) ? dc[4 * p + 3] : dc[4 * p + 1];
                int id = (rp & 1) ? ib : ia;
                rd16[p] = *(const half8*)(xh + (size_t)id * DF + c2 * 8);
            }
        } else {
#pragma unroll
            for (int p = 0; p < 8; ++p) {
                int id = hi ? sc[2 * p + 1] : sc[2 * p];
                rs32[p] = *(const float4*)(x + (size_t)id * DF + c * 4);
            }
#pragma unroll
            for (int p = 0; p < 8; ++p) {
                int id = hi ? dc[2 * p + 1] : dc[2 * p];
                rd32[p] = *(const float4*)(x + (size_t)id * DF + c * 4);
            }
        }

        // 2) issue ids for g + 2*gstride (scalar; lands by next iteration)
        int sn[16], dn[16];
        {
            int g2 = g + 2 * gstride; if (g2 >= ngroups) g2 = g;
            const int eb = g2 * 64 + w * 16;
            const int* __restrict__ ip = idx + eb;
            const int* __restrict__ jp = idx + n_edges + eb;
#pragma unroll
            for (int i = 0; i < 16; ++i) { sn[i] = ip[i]; dn[i] = jp[i]; }
        }

        // 3) MFMA on current LDS contents: D[hid][edge] = W1^T * diff
        floatx4 acc[4];
#pragma unroll
        for (int mt = 0; mt < 4; ++mt)
#pragma unroll
            for (int r = 0; r < 4; ++r)
                acc[mt][r] = (float)b1h[mt][r];

#pragma unroll
        for (int kb = 0; kb < 4; ++kb) {
            const half8 bf = *(const half8*)(ldsw + r16 * AST + kb * 32 + q * 8);
#pragma unroll
            for (int mt = 0; mt < 4; ++mt)
                acc[mt] = __builtin_amdgcn_mfma_f32_16x16x32_f16(wf[mt][kb], bf, acc[mt], 0, 0, 0);
        }

        // 4) epilogue: relu -> W2 -> reduce over q (2 shfl) -> sigmoid -> store
        float part = 0.f;
#pragma unroll
        for (int mt = 0; mt < 4; ++mt)
#pragma unroll
            for (int r = 0; r < 4; ++r)
                part = fmaf(fmaxf(acc[mt][r], 0.f), (float)w2h[mt][r], part);
        part += __shfl_xor(part, 16, 64);
        part += __shfl_xor(part, 32, 64);
        if (L < 16) {
            const int e = g * 64 + w * 16 + L;
            if (e < n_edges) out[e] = sigmoidf_(part + b2v);
        }

        // 5) diff next group's rows -> LDS (program-order after frag reads)
        if (F16X) {
#pragma unroll
            for (int p = 0; p < 4; ++p) {
                union { half8 h; uint4 u; } U;
                U.h = rs16[p] - rd16[p];
                U.u.x &= 0x7FFF7FFFu; U.u.y &= 0x7FFF7FFFu;
                U.u.z &= 0x7FFF7FFFu; U.u.w &= 0x7FFF7FFFu;
                *(half8*)(ldsw + (4 * p + rp) * AST + c2 * 8) = U.h;
            }
        } else {
#pragma unroll
            for (int p = 0; p < 8; ++p) {
                half4_t h;
                h[0] = (_Float16)fabsf(rs32[p].x - rd32[p].x);
                h[1] = (_Float16)fabsf(rs32[p].y - rd32[p].y);
                h[2] = (_Float16)fabsf(rs32[p].z - rd32[p].z);
                h[3] = (_Float16)fabsf(rs32[p].w - rd32[p].w);
                *(half4_t*)(ldsw + (2 * p + hi) * AST + c * 4) = h;
            }
        }

        // 6) advance id pipeline
#pragma unroll
        for (int i = 0; i < 16; ++i) { sc[i] = sn[i]; dc[i] = dn[i]; }
    }
}

// tail kernel (only if n_edges % 64 != 0 — never for this problem's 640000)
__global__ void edge_tail(const float* __restrict__ x, const int* __restrict__ idx,
                          const float* __restrict__ W1, const float* __restrict__ b1,
                          const float* __restrict__ W2, const float* __restrict__ b2,
                          float* __restrict__ out, int n_edges, int start)
{
    int e = start + blockIdx.x * blockDim.x + threadIdx.x;
    if (e >= n_edges) return;
    int s = idx[e], d = idx[n_edges + e];
    float t = b2[0];
    for (int j = 0; j < HID; ++j) {
        float h = b1[j];
        for (int k = 0; k < DF; ++k)
            h = fmaf(fabsf(x[(size_t)s * DF + k] - x[(size_t)d * DF + k]), W1[(size_t)k * HID + j], h);
        t = fmaf(fmaxf(h, 0.f), W2[j], t);
    }
    out[e] = sigmoidf_(t);
}

extern "C" void kernel_launch(void* const* d_in, const int* in_sizes, int n_in,
                              void* d_out, int out_size, void* d_ws, size_t ws_size,
                              hipStream_t stream) {
    const float* x   = (const float*)d_in[0];
    const int*   idx = (const int*)d_in[1];
    const float* W1  = (const float*)d_in[2];
    const float* b1  = (const float*)d_in[3];
    const float* W2  = (const float*)d_in[4];
    const float* b2  = (const float*)d_in[5];
    float* out = (float*)d_out;

    const int n_edges = in_sizes[1] / 2;      // indices is [2, n_edges]
    const int n_x     = in_sizes[0];          // node-feature element count
    const int ngroups = n_edges / 64;
    const int rem     = n_edges - ngroups * 64;

    const size_t xh_bytes = (size_t)n_x * sizeof(_Float16);
    const bool use_f16 = (ws_size >= xh_bytes) && (n_x % 4 == 0);

    int gstride = ngroups < 1280 ? ngroups : 1280;

    if (use_f16) {
        _Float16* xh = (_Float16*)d_ws;
        const int n4 = n_x / 4;
        cvt_x_f16<<<(n4 + 255) / 256, 256, 0, stream>>>(x, xh, n4);
        if (ngroups > 0)
            edge_mlp_v4<true><<<gstride, 256, 0, stream>>>(x, xh, idx, W1, b1, W2, b2,
                                                           out, n_edges, ngroups, gstride);
    } else {
        if (ngroups > 0)
            edge_mlp_v4<false><<<gstride, 256, 0, stream>>>(x, nullptr, idx, W1, b1, W2, b2,
                                                            out, n_edges, ngroups, gstride);
    }
    if (rem > 0)
        edge_tail<<<(rem + 63) / 64, 64, 0, stream>>>(x, idx, W1, b1, W2, b2,
                                                      out, n_edges, ngroups * 64);
}